// Round 4
// baseline (184.644 us; speedup 1.0000x reference)
//
#include <hip/hip_runtime.h>
#include <math.h>

constexpr int BATCH  = 32;
constexpr int HW     = 512 * 512;
constexpr int TPB    = 256;
constexpr int BPB    = 16;                 // blocks per batch
constexpr int BLOCKS = BATCH * BPB;        // 512 = 2 blocks/CU on 256 CUs
constexpr int CHUNK  = HW / BPB;           // 16384 elements per block
constexpr int NV4    = CHUNK / (TPB * 4);  // 16 float4 per thread per array
constexpr float EPS  = 1e-6f;

// ws layout:
//   int counters : cnt1[32] at int index [0..31], cnt2[32] at [32..63]
//   float partials: par[r*BLOCKS + blk], r in 0..4, starting at float index 64
//     r0=count, r1=sum(p*m), r2=sum(g*m), r3=sum(|p-shp|*m), r4=sum(|g-shg|*m)
constexpr int HDR = 64;

__device__ __forceinline__ float wave_reduce(float v) {
#pragma unroll
    for (int off = 32; off > 0; off >>= 1) v += __shfl_down(v, off, 64);
    return v;
}

__device__ __forceinline__ void arrive_and_wait(int* cnt) {
    // prior plain stores of this block's partials are released by the RMW
    if (threadIdx.x == 0) {
        __threadfence();
        __hip_atomic_fetch_add(cnt, 1, __ATOMIC_RELEASE, __HIP_MEMORY_SCOPE_AGENT);
    }
    __syncthreads();
    if ((threadIdx.x & 63) == 0) {
        int it = 0;
        while (__hip_atomic_load(cnt, __ATOMIC_ACQUIRE, __HIP_MEMORY_SCOPE_AGENT) < BPB
               && it < (1 << 20)) {
            __builtin_amdgcn_s_sleep(2);
            ++it;
        }
    }
    __syncthreads();
}

__device__ __forceinline__ float acq_load(const float* p) {
    return __hip_atomic_load(p, __ATOMIC_ACQUIRE, __HIP_MEMORY_SCOPE_AGENT);
}

__global__ __launch_bounds__(TPB, 2) void fused_loss(const float* __restrict__ pred,
                                                     const float* __restrict__ gt,
                                                     const int* __restrict__ mask,
                                                     float* __restrict__ out,
                                                     float* __restrict__ ws) {
    const int tid   = threadIdx.x;
    const int bid   = blockIdx.x;
    const int batch = bid >> 4;         // bid / BPB
    const int sub   = bid & (BPB - 1);
    const size_t base = (size_t)batch * HW + (size_t)sub * CHUNK;
    const int lane = tid & 63, wid = tid >> 6;

    int*   cnts = (int*)ws;
    float* par  = ws + HDR;

    __shared__ float sd[3][TPB / 64];
    __shared__ float tot[5];

    // ---------- phase 1: load all data into registers, masked count/sums ----------
    float4 p[NV4], g[NV4];
    unsigned mlo = 0u, mhi = 0u;
    float c = 0.f, sp = 0.f, sg = 0.f;
#pragma unroll
    for (int it = 0; it < NV4; ++it) {
        const size_t idx = base + (size_t)(it * TPB + tid) * 4;
        p[it] = *(const float4*)(pred + idx);
        g[it] = *(const float4*)(gt + idx);
        const int4 m = *(const int4*)(mask + idx);
        const unsigned b0 = (m.x != 0), b1 = (m.y != 0), b2 = (m.z != 0), b3 = (m.w != 0);
        const unsigned nib = b0 | (b1 << 1) | (b2 << 2) | (b3 << 3);
        if (it < 8) mlo |= nib << (4 * it); else mhi |= nib << (4 * (it - 8));
        const float m0 = (float)b0, m1 = (float)b1, m2 = (float)b2, m3 = (float)b3;
        c  += m0 + m1 + m2 + m3;
        sp += p[it].x * m0 + p[it].y * m1 + p[it].z * m2 + p[it].w * m3;
        sg += g[it].x * m0 + g[it].y * m1 + g[it].z * m2 + g[it].w * m3;
    }
    c = wave_reduce(c); sp = wave_reduce(sp); sg = wave_reduce(sg);
    if (lane == 0) { sd[0][wid] = c; sd[1][wid] = sp; sd[2][wid] = sg; }
    __syncthreads();
    if (tid == 0) {
        float t0 = 0.f, t1 = 0.f, t2 = 0.f;
#pragma unroll
        for (int i = 0; i < TPB / 64; ++i) { t0 += sd[0][i]; t1 += sd[1][i]; t2 += sd[2][i]; }
        par[0 * BLOCKS + bid] = t0;
        par[1 * BLOCKS + bid] = t1;
        par[2 * BLOCKS + bid] = t2;
    }
    __syncthreads();
    arrive_and_wait(&cnts[batch]);

    // ---------- phase 2: batch totals -> shifts; abs-sums from registers ----------
    {
        float t0 = 0.f, t1 = 0.f, t2 = 0.f;
        if (tid < BPB) {
            const int o = batch * BPB + tid;
            t0 = acq_load(&par[0 * BLOCKS + o]);
            t1 = acq_load(&par[1 * BLOCKS + o]);
            t2 = acq_load(&par[2 * BLOCKS + o]);
        }
        t0 = wave_reduce(t0); t1 = wave_reduce(t1); t2 = wave_reduce(t2);
        if (tid == 0) { tot[0] = t0; tot[1] = t1; tot[2] = t2; }
    }
    __syncthreads();
    const float count = fmaxf(tot[0], 1.0f);
    const float shp = tot[1] / count, shg = tot[2] / count;

    float ap = 0.f, ag = 0.f;
#pragma unroll
    for (int it = 0; it < NV4; ++it) {
        const unsigned w = (it < 8) ? mlo : mhi;
        const int sh = 4 * (it & 7);
        const float m0 = (float)((w >> (sh + 0)) & 1u);
        const float m1 = (float)((w >> (sh + 1)) & 1u);
        const float m2 = (float)((w >> (sh + 2)) & 1u);
        const float m3 = (float)((w >> (sh + 3)) & 1u);
        ap += fabsf(p[it].x - shp) * m0 + fabsf(p[it].y - shp) * m1
            + fabsf(p[it].z - shp) * m2 + fabsf(p[it].w - shp) * m3;
        ag += fabsf(g[it].x - shg) * m0 + fabsf(g[it].y - shg) * m1
            + fabsf(g[it].z - shg) * m2 + fabsf(g[it].w - shg) * m3;
    }
    ap = wave_reduce(ap); ag = wave_reduce(ag);
    if (lane == 0) { sd[0][wid] = ap; sd[1][wid] = ag; }
    __syncthreads();
    if (tid == 0) {
        float t3 = 0.f, t4 = 0.f;
#pragma unroll
        for (int i = 0; i < TPB / 64; ++i) { t3 += sd[0][i]; t4 += sd[1][i]; }
        par[3 * BLOCKS + bid] = t3;
        par[4 * BLOCKS + bid] = t4;
    }
    __syncthreads();
    arrive_and_wait(&cnts[32 + batch]);

    // ---------- phase 3: scales; write masked |pn - gn| from registers ----------
    {
        float t3 = 0.f, t4 = 0.f;
        if (tid < BPB) {
            const int o = batch * BPB + tid;
            t3 = acq_load(&par[3 * BLOCKS + o]);
            t4 = acq_load(&par[4 * BLOCKS + o]);
        }
        t3 = wave_reduce(t3); t4 = wave_reduce(t4);
        if (tid == 0) { tot[3] = t3; tot[4] = t4; }
    }
    __syncthreads();
    const float iscp = 1.0f / fmaxf(tot[3] / count, EPS);
    const float iscg = 1.0f / fmaxf(tot[4] / count, EPS);

#pragma unroll
    for (int it = 0; it < NV4; ++it) {
        const unsigned w = (it < 8) ? mlo : mhi;
        const int sh = 4 * (it & 7);
        float4 o;
        o.x = ((w >> (sh + 0)) & 1u) ? fabsf((p[it].x - shp) * iscp - (g[it].x - shg) * iscg) : 0.f;
        o.y = ((w >> (sh + 1)) & 1u) ? fabsf((p[it].y - shp) * iscp - (g[it].y - shg) * iscg) : 0.f;
        o.z = ((w >> (sh + 2)) & 1u) ? fabsf((p[it].z - shp) * iscp - (g[it].z - shg) * iscg) : 0.f;
        o.w = ((w >> (sh + 3)) & 1u) ? fabsf((p[it].w - shp) * iscp - (g[it].w - shg) * iscg) : 0.f;
        const size_t idx = base + (size_t)(it * TPB + tid) * 4;
        *(float4*)(out + idx) = o;
    }
}

extern "C" void kernel_launch(void* const* d_in, const int* in_sizes, int n_in,
                              void* d_out, int out_size, void* d_ws, size_t ws_size,
                              hipStream_t stream) {
    const float* pred = (const float*)d_in[0];
    const float* gt   = (const float*)d_in[1];
    const int*   mask = (const int*)d_in[2];
    float* out = (float*)d_out;
    float* ws  = (float*)d_ws;

    // zero the two arrival-counter arrays (64 ints) — capturable memset node
    hipMemsetAsync(ws, 0, HDR * sizeof(int), stream);
    fused_loss<<<dim3(BLOCKS), dim3(TPB), 0, stream>>>(pred, gt, mask, out, ws);
}